// Round 21
// baseline (45.039 us; speedup 1.0000x reference)
//
#include <hip/hip_runtime.h>

#define NTEST  16384
#define NTRAIN 8192
#define DIM    64
#define NCOLSPLIT 16
#define WPB    4                            // waves per block (256 threads)

typedef _Float16 f16x8  __attribute__((ext_vector_type(8)));
typedef float    f32x16 __attribute__((ext_vector_type(16)));

#define LOG2E 1.4426950408889634f

// Direct global->LDS DMA: no staging VGPRs, linear wave-contiguous LDS writes.
#define GLOAD_LDS16(gsrc, ldst)                                                     \
    __builtin_amdgcn_global_load_lds(                                               \
        (const __attribute__((address_space(1))) unsigned int*)(gsrc),              \
        (__attribute__((address_space(3))) unsigned int*)(ldst), 16, 0, 0)

// Rows [0,NTEST) = test_X -> A_hi = f16(x * s1) (PRE-SCALED by inv2*log2e so
// the MFMA emits the exp argument's dot term directly) + nx2 = cn*nx
// (+ zeroes out[row]). Rows [NTEST,..) = train_X -> B_hi = f16(x) UNSCALED
// in TILE-MAJOR layout + wt = alpha * exp2(cn*nt).
// Tile-major: for train row r, dim k:
//   flat = (r>>5)*2048 + (k>>4)*512 + (((k>>3)&1)*32 + (r&31))*8 + (k&7)
__global__ __launch_bounds__(256) void krr_prep(
    const float* __restrict__ test_X, const float* __restrict__ train_X,
    const float* __restrict__ alphas, const float* __restrict__ lengthscale,
    _Float16* __restrict__ A_hi, _Float16* __restrict__ B_hi,
    float* __restrict__ nx2, float* __restrict__ wt, float* __restrict__ out)
{
    int gwave = (blockIdx.x * 256 + threadIdx.x) >> 6;
    int lane  = threadIdx.x & 63;           // = dim index k
    bool is_test = gwave < NTEST;
    int row = is_test ? gwave : gwave - NTEST;
    const float* src = is_test ? test_X : train_X;

    float ls   = lengthscale[0];
    float inv2 = 1.0f / (ls * ls);
    float s1   = inv2 * LOG2E;               // dot coefficient (log2 domain)
    float cn   = -0.5f * inv2 * LOG2E;       // norm coefficient (log2 domain)

    float x = src[(size_t)row * DIM + lane];

    if (is_test) {
        A_hi[(size_t)row * DIM + lane] = (_Float16)(x * s1);  // pre-scaled
    } else {
        _Float16 h = (_Float16)x;                             // unscaled
        int t  = row >> 5, lr = row & 31;
        int kk = lane >> 4, hi = (lane >> 3) & 1, e = lane & 7;
        size_t dst = (size_t)t * 2048 + (size_t)kk * 512 + (size_t)(hi * 32 + lr) * 8 + e;
        B_hi[dst] = h;
    }

    float s = x * x;
    s += __shfl_xor(s, 1);  s += __shfl_xor(s, 2);  s += __shfl_xor(s, 4);
    s += __shfl_xor(s, 8);  s += __shfl_xor(s, 16); s += __shfl_xor(s, 32);
    if (lane == 0) {
        if (is_test) { nx2[row] = s * cn; out[row] = 0.0f; }
        else         wt[row]  = alphas[row] * __builtin_amdgcn_exp2f(cn * s);
    }
}

// B-REUSE x2 (round-20 conclusion: dur == SUM of pipe terms; shrink the
// largest term, LDS reads 10.3us). Each wave owns TWO 32-row sets (64 rows):
// one bh read feeds two independent seeded MFMA chains (C1<-ah1/nxcv1,
// C2<-ah2/nxcv2) -> LDS reads per element HALVE (537->268 MB). WG = 4 waves
// = 256 rows; staging/dbuf identical to r17-r19; stagger/setprio REMOVED
// (r20: -2.2us, falsified). __launch_bounds__(256,1) lifts the default
// 128-VGPR allocator cap (r14/r16 spill cause) — live set ~160 allocates
// freely; occupancy LDS-bound at 2 WG/CU (insensitive range, r12/13).
// Math per output element byte-identical to r19.
// K*alpha = exp2(C[r]) * wt[col], C = cn*nx + s1*dot via seeded chain.
__global__ __launch_bounds__(256, 1) void krr_mfma(
    const _Float16* __restrict__ A_hi, const _Float16* __restrict__ B_hi,
    const float* __restrict__ nx2, const float* __restrict__ wt,
    const float* __restrict__ lengthscale, float* __restrict__ out)
{
    alignas(16) __shared__ _Float16 BsA[8 * 2048];  // 32 KB (phase 0)
    alignas(16) __shared__ _Float16 BsB[8 * 2048];  // 32 KB (phase 1)
    __shared__ float wts[512];                      // 2 KB

    const int tid   = threadIdx.x;
    const int lane  = tid & 63;
    const int wave  = tid >> 6;
    const int rbase = blockIdx.x * 256 + wave * 64; // 64 rows per wave
    const int cb    = blockIdx.y;                   // col-split index

    // Wave w DMAs tiles {p*8+w*2, +1} (contiguous 4KB in tile-major): 8x1KB.
    #define STAGE8(p, buf)                                                      \
        {                                                                       \
            const _Float16* g0 = B_hi + ((size_t)cb * 16 + (p) * 8 + wave * 2) * 2048 \
                               + (size_t)lane * 8;                              \
            _Float16* l0 = (buf) + (size_t)(wave * 2) * 2048;                   \
            GLOAD_LDS16(g0,        l0);                                         \
            GLOAD_LDS16(g0 + 512,  l0 + 512);                                   \
            GLOAD_LDS16(g0 + 1024, l0 + 1024);                                  \
            GLOAD_LDS16(g0 + 1536, l0 + 1536);                                  \
            GLOAD_LDS16(g0 + 2048, l0 + 2048);                                  \
            GLOAD_LDS16(g0 + 2560, l0 + 2560);                                  \
            GLOAD_LDS16(g0 + 3072, l0 + 3072);                                  \
            GLOAD_LDS16(g0 + 3584, l0 + 3584);                                  \
        }

    // 8 tiles of phase p: ONE bh read feeds BOTH row-sets' chains; next
    // tile's bh loads issued after the MFMAs (r18 rotation), before the
    // epilogue. Loop stays '#pragma unroll 1' (live-range barrier).
    #define COMPUTE8(p, buf)                                                    \
        {                                                                       \
            const _Float16* pbase = (buf) + (size_t)lane * 8;                   \
            f16x8 bh[4];                                                        \
            _Pragma("unroll")                                                   \
            for (int kk = 0; kk < 4; ++kk)                                      \
                bh[kk] = *reinterpret_cast<const f16x8*>(pbase + kk * 512);     \
            _Pragma("unroll 1")                                                 \
            for (int lt = 0; lt < 8; ++lt) {                                    \
                f32x16 C1 = __builtin_amdgcn_mfma_f32_32x32x16_f16(ah1[0], bh[0], nxcv1, 0, 0, 0); \
                f32x16 C2 = __builtin_amdgcn_mfma_f32_32x32x16_f16(ah2[0], bh[0], nxcv2, 0, 0, 0); \
                _Pragma("unroll")                                               \
                for (int kk = 1; kk < 4; ++kk) {                                \
                    C1 = __builtin_amdgcn_mfma_f32_32x32x16_f16(ah1[kk], bh[kk], C1, 0, 0, 0); \
                    C2 = __builtin_amdgcn_mfma_f32_32x32x16_f16(ah2[kk], bh[kk], C2, 0, 0, 0); \
                }                                                               \
                const float w = wts[((p) * 8 + lt) * 32 + (lane & 31)];         \
                if (lt < 7) {                                                   \
                    const _Float16* pn = pbase + (size_t)(lt + 1) * 2048;       \
                    _Pragma("unroll")                                           \
                    for (int kk = 0; kk < 4; ++kk)                              \
                        bh[kk] = *reinterpret_cast<const f16x8*>(pn + kk * 512); \
                }                                                               \
                _Pragma("unroll")                                               \
                for (int r = 0; r < 16; ++r) {                                  \
                    acc1[r] = fmaf(__builtin_amdgcn_exp2f(C1[r]), w, acc1[r]);  \
                    acc2[r] = fmaf(__builtin_amdgcn_exp2f(C2[r]), w, acc2[r]);  \
                }                                                               \
            }                                                                   \
        }

    // Issue phase-0 stage + weights immediately (256 threads, 512 wts).
    STAGE8(0, BsA);
    wts[tid]       = wt[cb * 512 + tid];
    wts[tid + 256] = wt[cb * 512 + tid + 256];

    const int arow1 = rbase + (lane & 31);
    const int arow2 = arow1 + 32;
    const int koff  = (lane >> 5) * 8;       // canonical k-map, same for A and B

    // A fragments for both row-sets (pre-scaled by s1): 8 x 16B = 32 VGPRs
    f16x8 ah1[4], ah2[4];
    #pragma unroll
    for (int kk = 0; kk < 4; ++kk) {
        ah1[kk] = *reinterpret_cast<const f16x8*>(A_hi + (size_t)arow1 * DIM + kk * 16 + koff);
        ah2[kk] = *reinterpret_cast<const f16x8*>(A_hi + (size_t)arow2 * DIM + kk * 16 + koff);
    }

    // C-seeds: cn*nx for the 16 C/D rows of each row-set.
    f32x16 nxcv1, nxcv2;
    #pragma unroll
    for (int r = 0; r < 16; ++r) {
        int row = (r & 3) + 8 * (r >> 2) + 4 * (lane >> 5);
        nxcv1[r] = nx2[rbase + row];
        nxcv2[r] = nx2[rbase + 32 + row];
    }

    float acc1[16], acc2[16];
    #pragma unroll
    for (int r = 0; r < 16; ++r) { acc1[r] = 0.0f; acc2[r] = 0.0f; }

    __syncthreads();              // BsA ready (the one exposed stage wait)

    STAGE8(1, BsB);               // issued now; latency hidden under COMPUTE8(0)
    COMPUTE8(0, BsA);

    __syncthreads();              // drains BsB loads (covered by compute above)

    COMPUTE8(1, BsB);

    #undef STAGE8
    #undef COMPUTE8

    // Reductions + atomics for both row-sets.
    #pragma unroll
    for (int r = 0; r < 16; ++r) {
        float v = acc1[r];
        v += __shfl_xor(v, 1);  v += __shfl_xor(v, 2);  v += __shfl_xor(v, 4);
        v += __shfl_xor(v, 8);  v += __shfl_xor(v, 16);
        if ((lane & 31) == 0) {
            int row = (r & 3) + 8 * (r >> 2) + 4 * (lane >> 5);
            atomicAdd(&out[rbase + row], v);
        }
    }
    #pragma unroll
    for (int r = 0; r < 16; ++r) {
        float v = acc2[r];
        v += __shfl_xor(v, 1);  v += __shfl_xor(v, 2);  v += __shfl_xor(v, 4);
        v += __shfl_xor(v, 8);  v += __shfl_xor(v, 16);
        if ((lane & 31) == 0) {
            int row = (r & 3) + 8 * (r >> 2) + 4 * (lane >> 5);
            atomicAdd(&out[rbase + 32 + row], v);
        }
    }
}

// ---------------- fallback (round-1 kernel, known-good) ----------------
#define TCHUNK 512
#define NCHUNK (NTRAIN / TCHUNK)
__global__ __launch_bounds__(256, 4) void krr_main(
    const float* __restrict__ test_X, const float* __restrict__ train_X,
    const float* __restrict__ alphas, const float* __restrict__ lengthscale,
    float* __restrict__ out)
{
    __shared__ float nt_lds[TCHUNK];
    __shared__ float al_lds[TCHUNK];
    const int tid = threadIdx.x;
    const int i   = blockIdx.x * 256 + tid;
    const int j0  = blockIdx.y * TCHUNK;
    const float ls   = lengthscale[0];
    const float inv2 = 1.0f / (ls * ls);
    for (int jj = tid; jj < TCHUNK; jj += 256) {
        const float4* tr = reinterpret_cast<const float4*>(train_X + (size_t)(j0 + jj) * DIM);
        float s = 0.f;
        #pragma unroll
        for (int k = 0; k < DIM / 4; ++k) {
            float4 t = tr[k];
            s += t.x * t.x + t.y * t.y + t.z * t.z + t.w * t.w;
        }
        nt_lds[jj] = s * inv2;
        al_lds[jj] = alphas[j0 + jj];
    }
    __syncthreads();
    float xr[DIM]; float nxv = 0.f;
    {
        const float4* xp = reinterpret_cast<const float4*>(test_X + (size_t)i * DIM);
        #pragma unroll
        for (int k = 0; k < DIM / 4; ++k) {
            float4 v = xp[k];
            xr[4*k+0] = v.x; xr[4*k+1] = v.y; xr[4*k+2] = v.z; xr[4*k+3] = v.w;
            nxv += v.x*v.x + v.y*v.y + v.z*v.z + v.w*v.w;
        }
        nxv *= inv2;
        #pragma unroll
        for (int k = 0; k < DIM; ++k) xr[k] *= inv2;
    }
    float acc = 0.f;
    for (int jj = 0; jj < TCHUNK; ++jj) {
        const float* trow = train_X + (size_t)(j0 + jj) * DIM;
        float d0 = 0.f, d1 = 0.f, d2 = 0.f, d3 = 0.f;
        #pragma unroll
        for (int k4 = 0; k4 < DIM / 4; ++k4) {
            float4 t = reinterpret_cast<const float4*>(trow)[k4];
            d0 = fmaf(xr[4*k4+0], t.x, d0);
            d1 = fmaf(xr[4*k4+1], t.y, d1);
            d2 = fmaf(xr[4*k4+2], t.z, d2);
            d3 = fmaf(xr[4*k4+3], t.w, d3);
        }
        float dot = (d0 + d1) + (d2 + d3);
        float sq  = nxv + nt_lds[jj] - 2.0f * dot;
        sq = fmaxf(sq, 0.0f);
        acc = fmaf(__expf(-0.5f * sq), al_lds[jj], acc);
    }
    atomicAdd(&out[i], acc);
}

extern "C" void kernel_launch(void* const* d_in, const int* in_sizes, int n_in,
                              void* d_out, int out_size, void* d_ws, size_t ws_size,
                              hipStream_t stream) {
    const float* test_X      = (const float*)d_in[0];
    const float* train_X     = (const float*)d_in[1];
    const float* alphas      = (const float*)d_in[2];
    const float* lengthscale = (const float*)d_in[3];
    float* out = (float*)d_out;

    const size_t need = (size_t)(NTEST + NTRAIN) * DIM * sizeof(_Float16)
                      + (NTEST + NTRAIN) * sizeof(float);
    if (ws_size >= need) {
        _Float16* A_hi = (_Float16*)d_ws;
        _Float16* B_hi = A_hi + (size_t)NTEST * DIM;
        float*    nx2  = (float*)(B_hi + (size_t)NTRAIN * DIM);
        float*    wtp  = nx2 + NTEST;

        // prep also zeroes `out` (memset launch folded in).
        krr_prep<<<(NTEST + NTRAIN) / 4, 256, 0, stream>>>(
            test_X, train_X, alphas, lengthscale, A_hi, B_hi, nx2, wtp, out);

        dim3 grid(NTEST / 256, NCOLSPLIT);
        krr_mfma<<<grid, 64 * WPB, 0, stream>>>(A_hi, B_hi, nx2, wtp,
                                                lengthscale, out);
    } else {
        hipMemsetAsync(out, 0, NTEST * sizeof(float), stream);
        dim3 grid(NTEST / 256, NCHUNK);
        krr_main<<<grid, 256, 0, stream>>>(test_X, train_X, alphas, lengthscale, out);
    }
}

// Round 22
// 45.012 us; speedup vs baseline: 1.0006x; 1.0006x over previous
//
#include <hip/hip_runtime.h>

#define NTEST  16384
#define NTRAIN 8192
#define DIM    64
#define NCOLSPLIT 16
#define WPB    8                            // waves per block (512 threads)

typedef _Float16 f16x8  __attribute__((ext_vector_type(8)));
typedef float    f32x16 __attribute__((ext_vector_type(16)));

#define LOG2E 1.4426950408889634f

// Direct global->LDS DMA: no staging VGPRs, linear wave-contiguous LDS writes.
#define GLOAD_LDS16(gsrc, ldst)                                                     \
    __builtin_amdgcn_global_load_lds(                                               \
        (const __attribute__((address_space(1))) unsigned int*)(gsrc),              \
        (__attribute__((address_space(3))) unsigned int*)(ldst), 16, 0, 0)

// Rows [0,NTEST) = test_X -> A_hi = f16(x * s1) (PRE-SCALED by inv2*log2e so
// the MFMA emits the exp argument's dot term directly) + nx2 = cn*nx
// (+ zeroes out[row]). Rows [NTEST,..) = train_X -> B_hi = f16(x) UNSCALED
// in TILE-MAJOR layout + wt = alpha * exp2(cn*nt).
// Tile-major: for train row r, dim k:
//   flat = (r>>5)*2048 + (k>>4)*512 + (((k>>3)&1)*32 + (r&31))*8 + (k&7)
__global__ __launch_bounds__(256) void krr_prep(
    const float* __restrict__ test_X, const float* __restrict__ train_X,
    const float* __restrict__ alphas, const float* __restrict__ lengthscale,
    _Float16* __restrict__ A_hi, _Float16* __restrict__ B_hi,
    float* __restrict__ nx2, float* __restrict__ wt, float* __restrict__ out)
{
    int gwave = (blockIdx.x * 256 + threadIdx.x) >> 6;
    int lane  = threadIdx.x & 63;           // = dim index k
    bool is_test = gwave < NTEST;
    int row = is_test ? gwave : gwave - NTEST;
    const float* src = is_test ? test_X : train_X;

    float ls   = lengthscale[0];
    float inv2 = 1.0f / (ls * ls);
    float s1   = inv2 * LOG2E;               // dot coefficient (log2 domain)
    float cn   = -0.5f * inv2 * LOG2E;       // norm coefficient (log2 domain)

    float x = src[(size_t)row * DIM + lane];

    if (is_test) {
        A_hi[(size_t)row * DIM + lane] = (_Float16)(x * s1);  // pre-scaled
    } else {
        _Float16 h = (_Float16)x;                             // unscaled
        int t  = row >> 5, lr = row & 31;
        int kk = lane >> 4, hi = (lane >> 3) & 1, e = lane & 7;
        size_t dst = (size_t)t * 2048 + (size_t)kk * 512 + (size_t)(hi * 32 + lr) * 8 + e;
        B_hi[dst] = h;
    }

    float s = x * x;
    s += __shfl_xor(s, 1);  s += __shfl_xor(s, 2);  s += __shfl_xor(s, 4);
    s += __shfl_xor(s, 8);  s += __shfl_xor(s, 16); s += __shfl_xor(s, 32);
    if (lane == 0) {
        if (is_test) { nx2[row] = s * cn; out[row] = 0.0f; }
        else         wt[row]  = alphas[row] * __builtin_amdgcn_exp2f(cn * s);
    }
}

// B-REUSE x2 AT r19 RESIDENCY (r21 post-mortem: the halved-LDS body was
// right, but a 256-thread WG at 66KB LDS dropped residency to 2 waves/SIMD
// and cost +12us). This round: 512-thread WG = 8 waves x 64 rows = 512
// rows/WG; same 66KB dbuf -> 2 WG/CU but 16 waves/CU = 4/SIMD (r19-equal).
// Wave w stages tile p*8+w (r17/r19 staging verbatim); one bh read feeds
// TWO seeded chains (C1<-ah1/nxcv1, C2<-ah2/nxcv2) -> LDS reads halved.
// VGPR 96 measured at this body (r21); launch_bounds(512,1) leaves the
// allocator alone. Math per output element byte-identical to r19/r21.
// K*alpha = exp2(C[r]) * wt[col], C = cn*nx + s1*dot via seeded chain.
__global__ __launch_bounds__(512, 1) void krr_mfma(
    const _Float16* __restrict__ A_hi, const _Float16* __restrict__ B_hi,
    const float* __restrict__ nx2, const float* __restrict__ wt,
    const float* __restrict__ lengthscale, float* __restrict__ out)
{
    alignas(16) __shared__ _Float16 BsA[8 * 2048];  // 32 KB (phase 0)
    alignas(16) __shared__ _Float16 BsB[8 * 2048];  // 32 KB (phase 1)
    __shared__ float wts[512];                      // 2 KB

    const int tid   = threadIdx.x;
    const int lane  = tid & 63;
    const int wave  = tid >> 6;
    const int rbase = blockIdx.x * 512 + wave * 64; // 64 rows per wave
    const int cb    = blockIdx.y;                   // col-split index

    // Wave w DMAs tile (p*8 + w) of the strip: 4 x 1KB global_load_lds.
    #define STAGE8(p, buf)                                                      \
        {                                                                       \
            const _Float16* gt = B_hi + ((size_t)cb * 16 + (p) * 8 + wave) * 2048 \
                               + (size_t)lane * 8;                              \
            _Float16* lt0 = (buf) + (size_t)wave * 2048;                        \
            GLOAD_LDS16(gt,        lt0);                                        \
            GLOAD_LDS16(gt + 512,  lt0 + 512);                                  \
            GLOAD_LDS16(gt + 1024, lt0 + 1024);                                 \
            GLOAD_LDS16(gt + 1536, lt0 + 1536);                                 \
        }

    // 8 tiles of phase p: ONE bh read feeds BOTH row-sets' chains; next
    // tile's bh loads issued after the MFMAs (r18 rotation), before the
    // epilogue. Loop stays '#pragma unroll 1' (live-range barrier).
    #define COMPUTE8(p, buf)                                                    \
        {                                                                       \
            const _Float16* pbase = (buf) + (size_t)lane * 8;                   \
            f16x8 bh[4];                                                        \
            _Pragma("unroll")                                                   \
            for (int kk = 0; kk < 4; ++kk)                                      \
                bh[kk] = *reinterpret_cast<const f16x8*>(pbase + kk * 512);     \
            _Pragma("unroll 1")                                                 \
            for (int lt = 0; lt < 8; ++lt) {                                    \
                f32x16 C1 = __builtin_amdgcn_mfma_f32_32x32x16_f16(ah1[0], bh[0], nxcv1, 0, 0, 0); \
                f32x16 C2 = __builtin_amdgcn_mfma_f32_32x32x16_f16(ah2[0], bh[0], nxcv2, 0, 0, 0); \
                _Pragma("unroll")                                               \
                for (int kk = 1; kk < 4; ++kk) {                                \
                    C1 = __builtin_amdgcn_mfma_f32_32x32x16_f16(ah1[kk], bh[kk], C1, 0, 0, 0); \
                    C2 = __builtin_amdgcn_mfma_f32_32x32x16_f16(ah2[kk], bh[kk], C2, 0, 0, 0); \
                }                                                               \
                const float w = wts[((p) * 8 + lt) * 32 + (lane & 31)];         \
                if (lt < 7) {                                                   \
                    const _Float16* pn = pbase + (size_t)(lt + 1) * 2048;       \
                    _Pragma("unroll")                                           \
                    for (int kk = 0; kk < 4; ++kk)                              \
                        bh[kk] = *reinterpret_cast<const f16x8*>(pn + kk * 512); \
                }                                                               \
                _Pragma("unroll")                                               \
                for (int r = 0; r < 16; ++r) {                                  \
                    acc1[r] = fmaf(__builtin_amdgcn_exp2f(C1[r]), w, acc1[r]);  \
                    acc2[r] = fmaf(__builtin_amdgcn_exp2f(C2[r]), w, acc2[r]);  \
                }                                                               \
            }                                                                   \
        }

    // Issue phase-0 stage + weights immediately (512 threads, 512 wts).
    STAGE8(0, BsA);
    wts[tid] = wt[cb * 512 + tid];

    const int arow1 = rbase + (lane & 31);
    const int arow2 = arow1 + 32;
    const int koff  = (lane >> 5) * 8;       // canonical k-map, same for A and B

    // A fragments for both row-sets (pre-scaled by s1): 8 x 16B = 32 VGPRs
    f16x8 ah1[4], ah2[4];
    #pragma unroll
    for (int kk = 0; kk < 4; ++kk) {
        ah1[kk] = *reinterpret_cast<const f16x8*>(A_hi + (size_t)arow1 * DIM + kk * 16 + koff);
        ah2[kk] = *reinterpret_cast<const f16x8*>(A_hi + (size_t)arow2 * DIM + kk * 16 + koff);
    }

    // C-seeds: cn*nx for the 16 C/D rows of each row-set.
    f32x16 nxcv1, nxcv2;
    #pragma unroll
    for (int r = 0; r < 16; ++r) {
        int row = (r & 3) + 8 * (r >> 2) + 4 * (lane >> 5);
        nxcv1[r] = nx2[rbase + row];
        nxcv2[r] = nx2[rbase + 32 + row];
    }

    float acc1[16], acc2[16];
    #pragma unroll
    for (int r = 0; r < 16; ++r) { acc1[r] = 0.0f; acc2[r] = 0.0f; }

    __syncthreads();              // BsA ready (the one exposed stage wait)

    STAGE8(1, BsB);               // issued now; latency hidden under COMPUTE8(0)
    COMPUTE8(0, BsA);

    __syncthreads();              // drains BsB loads (covered by compute above)

    COMPUTE8(1, BsB);

    #undef STAGE8
    #undef COMPUTE8

    // Reductions + atomics for both row-sets.
    #pragma unroll
    for (int r = 0; r < 16; ++r) {
        float v = acc1[r];
        v += __shfl_xor(v, 1);  v += __shfl_xor(v, 2);  v += __shfl_xor(v, 4);
        v += __shfl_xor(v, 8);  v += __shfl_xor(v, 16);
        if ((lane & 31) == 0) {
            int row = (r & 3) + 8 * (r >> 2) + 4 * (lane >> 5);
            atomicAdd(&out[rbase + row], v);
        }
    }
    #pragma unroll
    for (int r = 0; r < 16; ++r) {
        float v = acc2[r];
        v += __shfl_xor(v, 1);  v += __shfl_xor(v, 2);  v += __shfl_xor(v, 4);
        v += __shfl_xor(v, 8);  v += __shfl_xor(v, 16);
        if ((lane & 31) == 0) {
            int row = (r & 3) + 8 * (r >> 2) + 4 * (lane >> 5);
            atomicAdd(&out[rbase + 32 + row], v);
        }
    }
}

// ---------------- fallback (round-1 kernel, known-good) ----------------
#define TCHUNK 512
#define NCHUNK (NTRAIN / TCHUNK)
__global__ __launch_bounds__(256, 4) void krr_main(
    const float* __restrict__ test_X, const float* __restrict__ train_X,
    const float* __restrict__ alphas, const float* __restrict__ lengthscale,
    float* __restrict__ out)
{
    __shared__ float nt_lds[TCHUNK];
    __shared__ float al_lds[TCHUNK];
    const int tid = threadIdx.x;
    const int i   = blockIdx.x * 256 + tid;
    const int j0  = blockIdx.y * TCHUNK;
    const float ls   = lengthscale[0];
    const float inv2 = 1.0f / (ls * ls);
    for (int jj = tid; jj < TCHUNK; jj += 256) {
        const float4* tr = reinterpret_cast<const float4*>(train_X + (size_t)(j0 + jj) * DIM);
        float s = 0.f;
        #pragma unroll
        for (int k = 0; k < DIM / 4; ++k) {
            float4 t = tr[k];
            s += t.x * t.x + t.y * t.y + t.z * t.z + t.w * t.w;
        }
        nt_lds[jj] = s * inv2;
        al_lds[jj] = alphas[j0 + jj];
    }
    __syncthreads();
    float xr[DIM]; float nxv = 0.f;
    {
        const float4* xp = reinterpret_cast<const float4*>(test_X + (size_t)i * DIM);
        #pragma unroll
        for (int k = 0; k < DIM / 4; ++k) {
            float4 v = xp[k];
            xr[4*k+0] = v.x; xr[4*k+1] = v.y; xr[4*k+2] = v.z; xr[4*k+3] = v.w;
            nxv += v.x*v.x + v.y*v.y + v.z*v.z + v.w*v.w;
        }
        nxv *= inv2;
        #pragma unroll
        for (int k = 0; k < DIM; ++k) xr[k] *= inv2;
    }
    float acc = 0.f;
    for (int jj = 0; jj < TCHUNK; ++jj) {
        const float* trow = train_X + (size_t)(j0 + jj) * DIM;
        float d0 = 0.f, d1 = 0.f, d2 = 0.f, d3 = 0.f;
        #pragma unroll
        for (int k4 = 0; k4 < DIM / 4; ++k4) {
            float4 t = reinterpret_cast<const float4*>(trow)[k4];
            d0 = fmaf(xr[4*k4+0], t.x, d0);
            d1 = fmaf(xr[4*k4+1], t.y, d1);
            d2 = fmaf(xr[4*k4+2], t.z, d2);
            d3 = fmaf(xr[4*k4+3], t.w, d3);
        }
        float dot = (d0 + d1) + (d2 + d3);
        float sq  = nxv + nt_lds[jj] - 2.0f * dot;
        sq = fmaxf(sq, 0.0f);
        acc = fmaf(__expf(-0.5f * sq), al_lds[jj], acc);
    }
    atomicAdd(&out[i], acc);
}

extern "C" void kernel_launch(void* const* d_in, const int* in_sizes, int n_in,
                              void* d_out, int out_size, void* d_ws, size_t ws_size,
                              hipStream_t stream) {
    const float* test_X      = (const float*)d_in[0];
    const float* train_X     = (const float*)d_in[1];
    const float* alphas      = (const float*)d_in[2];
    const float* lengthscale = (const float*)d_in[3];
    float* out = (float*)d_out;

    const size_t need = (size_t)(NTEST + NTRAIN) * DIM * sizeof(_Float16)
                      + (NTEST + NTRAIN) * sizeof(float);
    if (ws_size >= need) {
        _Float16* A_hi = (_Float16*)d_ws;
        _Float16* B_hi = A_hi + (size_t)NTEST * DIM;
        float*    nx2  = (float*)(B_hi + (size_t)NTRAIN * DIM);
        float*    wtp  = nx2 + NTEST;

        // prep also zeroes `out` (memset launch folded in).
        krr_prep<<<(NTEST + NTRAIN) / 4, 256, 0, stream>>>(
            test_X, train_X, alphas, lengthscale, A_hi, B_hi, nx2, wtp, out);

        dim3 grid(NTEST / 512, NCOLSPLIT);
        krr_mfma<<<grid, 64 * WPB, 0, stream>>>(A_hi, B_hi, nx2, wtp,
                                                lengthscale, out);
    } else {
        hipMemsetAsync(out, 0, NTEST * sizeof(float), stream);
        dim3 grid(NTEST / 256, NCHUNK);
        krr_main<<<grid, 256, 0, stream>>>(test_X, train_X, alphas, lengthscale, out);
    }
}

// Round 23
// 38.579 us; speedup vs baseline: 1.1674x; 1.1667x over previous
//
#include <hip/hip_runtime.h>

#define NTEST  16384
#define NTRAIN 8192
#define DIM    64
#define NCOLSPLIT 8
#define WPB    8                            // waves per block (512 threads)

typedef _Float16 f16x8  __attribute__((ext_vector_type(8)));
typedef float    f32x16 __attribute__((ext_vector_type(16)));

#define LOG2E 1.4426950408889634f

// Direct global->LDS DMA: no staging VGPRs, linear wave-contiguous LDS writes.
#define GLOAD_LDS16(gsrc, ldst)                                                     \
    __builtin_amdgcn_global_load_lds(                                               \
        (const __attribute__((address_space(1))) unsigned int*)(gsrc),              \
        (__attribute__((address_space(3))) unsigned int*)(ldst), 16, 0, 0)

// Rows [0,NTEST) = test_X -> A_hi = f16(x * s1) (PRE-SCALED by inv2*log2e so
// the MFMA emits the exp argument's dot term directly) + nx2 = cn*nx
// (+ zeroes out[row]). Rows [NTEST,..) = train_X -> B_hi = f16(x) UNSCALED
// in TILE-MAJOR layout + wt = alpha * exp2(cn*nt).
// Tile-major: for train row r, dim k:
//   flat = (r>>5)*2048 + (k>>4)*512 + (((k>>3)&1)*32 + (r&31))*8 + (k&7)
__global__ __launch_bounds__(256) void krr_prep(
    const float* __restrict__ test_X, const float* __restrict__ train_X,
    const float* __restrict__ alphas, const float* __restrict__ lengthscale,
    _Float16* __restrict__ A_hi, _Float16* __restrict__ B_hi,
    float* __restrict__ nx2, float* __restrict__ wt, float* __restrict__ out)
{
    int gwave = (blockIdx.x * 256 + threadIdx.x) >> 6;
    int lane  = threadIdx.x & 63;           // = dim index k
    bool is_test = gwave < NTEST;
    int row = is_test ? gwave : gwave - NTEST;
    const float* src = is_test ? test_X : train_X;

    float ls   = lengthscale[0];
    float inv2 = 1.0f / (ls * ls);
    float s1   = inv2 * LOG2E;               // dot coefficient (log2 domain)
    float cn   = -0.5f * inv2 * LOG2E;       // norm coefficient (log2 domain)

    float x = src[(size_t)row * DIM + lane];

    if (is_test) {
        A_hi[(size_t)row * DIM + lane] = (_Float16)(x * s1);  // pre-scaled
    } else {
        _Float16 h = (_Float16)x;                             // unscaled
        int t  = row >> 5, lr = row & 31;
        int kk = lane >> 4, hi = (lane >> 3) & 1, e = lane & 7;
        size_t dst = (size_t)t * 2048 + (size_t)kk * 512 + (size_t)(hi * 32 + lr) * 8 + e;
        B_hi[dst] = h;
    }

    float s = x * x;
    s += __shfl_xor(s, 1);  s += __shfl_xor(s, 2);  s += __shfl_xor(s, 4);
    s += __shfl_xor(s, 8);  s += __shfl_xor(s, 16); s += __shfl_xor(s, 32);
    if (lane == 0) {
        if (is_test) { nx2[row] = s * cn; out[row] = 0.0f; }
        else         wt[row]  = alphas[row] * __builtin_amdgcn_exp2f(cn * s);
    }
}

// r19 STRUCTURE (the 38.8us champion) + TPW 16->32 (r11 precedent: 8->16
// was +12% from setup/drain amortization; r22 falsified B-reuse at equal
// residency, so per-wave overhead is the one term with a measured-positive
// lever left). Strip = 1024 cols = 32 tiles, 4 phases x 8 tiles through the
// same two 32KB buffers; every barrier's vmcnt-drain covered by a preceding
// 8-tile compute. Grid (64,8) = exactly 2 WG/CU (no tail); 68KB LDS.
// Compute/staging/prep byte-identical to r19; 4 unroll-1 COMPUTE8 instances
// share only acc/nxcv/ah across barriers (~110 VGPR peak, under the 128
// cliff — r16's spill was FULLY-UNROLLED compute, not this).
// K*alpha = exp2(C[r]) * wt[col], C = cn*nx + s1*dot via seeded chain.
__global__ __launch_bounds__(512, 1) void krr_mfma(
    const _Float16* __restrict__ A_hi, const _Float16* __restrict__ B_hi,
    const float* __restrict__ nx2, const float* __restrict__ wt,
    const float* __restrict__ lengthscale, float* __restrict__ out)
{
    alignas(16) __shared__ _Float16 BsA[8 * 2048];  // 32 KB (even phases)
    alignas(16) __shared__ _Float16 BsB[8 * 2048];  // 32 KB (odd phases)
    __shared__ float wts[1024];                     // 4 KB

    const int tid   = threadIdx.x;
    const int lane  = tid & 63;
    const int wave  = tid >> 6;
    const int rbase = blockIdx.x * 256 + wave * 32;
    const int cb    = blockIdx.y;                   // col-split index

    // Wave w DMAs tile (p*8 + w) of the 32-tile strip: 4 x 1KB DMA.
    #define STAGE8(p, buf)                                                      \
        {                                                                       \
            const _Float16* gt = B_hi + ((size_t)cb * 32 + (p) * 8 + wave) * 2048 \
                               + (size_t)lane * 8;                              \
            _Float16* lt0 = (buf) + (size_t)wave * 2048;                        \
            GLOAD_LDS16(gt,        lt0);                                        \
            GLOAD_LDS16(gt + 512,  lt0 + 512);                                  \
            GLOAD_LDS16(gt + 1024, lt0 + 1024);                                 \
            GLOAD_LDS16(gt + 1536, lt0 + 1536);                                 \
        }

    // Compute 8 tiles of phase p: pair-rotated (r18), chains seeded with
    // nxcv via the first MFMA's C operand (r19); epilogue = exp2 + fma.
    // MUST stay a '#pragma unroll 1' loop (live-range barrier).
    #define COMPUTE8(p, buf)                                                    \
        {                                                                       \
            const _Float16* pbase = (buf) + (size_t)lane * 8;                   \
            f16x8 bhA[4], bhB[4];                                               \
            _Pragma("unroll")                                                   \
            for (int kk = 0; kk < 4; ++kk) {                                    \
                bhA[kk] = *reinterpret_cast<const f16x8*>(pbase + kk * 512);    \
                bhB[kk] = *reinterpret_cast<const f16x8*>(pbase + 2048 + kk * 512); \
            }                                                                   \
            _Pragma("unroll 1")                                                 \
            for (int lt = 0; lt < 8; lt += 2) {                                 \
                f32x16 CA = __builtin_amdgcn_mfma_f32_32x32x16_f16(ah[0], bhA[0], nxcv, 0, 0, 0); \
                f32x16 CB = __builtin_amdgcn_mfma_f32_32x32x16_f16(ah[0], bhB[0], nxcv, 0, 0, 0); \
                _Pragma("unroll")                                               \
                for (int kk = 1; kk < 4; ++kk) {                                \
                    CA = __builtin_amdgcn_mfma_f32_32x32x16_f16(ah[kk], bhA[kk], CA, 0, 0, 0); \
                    CB = __builtin_amdgcn_mfma_f32_32x32x16_f16(ah[kk], bhB[kk], CB, 0, 0, 0); \
                }                                                               \
                const int wtb = ((p) * 8 + lt) * 32 + (lane & 31);              \
                const float wA = wts[wtb];                                      \
                const float wB = wts[wtb + 32];                                 \
                if (lt < 6) {                                                   \
                    const _Float16* pn = pbase + (size_t)(lt + 2) * 2048;       \
                    _Pragma("unroll")                                           \
                    for (int kk = 0; kk < 4; ++kk) {                            \
                        bhA[kk] = *reinterpret_cast<const f16x8*>(pn + kk * 512); \
                        bhB[kk] = *reinterpret_cast<const f16x8*>(pn + 2048 + kk * 512); \
                    }                                                           \
                }                                                               \
                _Pragma("unroll")                                               \
                for (int r = 0; r < 16; ++r) {                                  \
                    acc[r] = fmaf(__builtin_amdgcn_exp2f(CA[r]), wA, acc[r]);   \
                    acc[r] = fmaf(__builtin_amdgcn_exp2f(CB[r]), wB, acc[r]);   \
                }                                                               \
            }                                                                   \
        }

    // Issue phase-0 stage + weights immediately (512 threads, 1024 wts).
    STAGE8(0, BsA);
    wts[tid]       = wt[cb * 1024 + tid];
    wts[tid + 512] = wt[cb * 1024 + tid + 512];

    const int arow = rbase + (lane & 31);
    const int koff = (lane >> 5) * 8;        // canonical k-map, same for A and B

    // A fragments (pre-scaled by s1), loop-invariant: 4 x 16B = 16 VGPRs
    f16x8 ah[4];
    #pragma unroll
    for (int kk = 0; kk < 4; ++kk)
        ah[kk] = *reinterpret_cast<const f16x8*>(A_hi + (size_t)arow * DIM + kk * 16 + koff);

    // C-seed: cn*nx for the 16 C/D rows this lane holds.
    f32x16 nxcv;
    #pragma unroll
    for (int r = 0; r < 16; ++r) {
        int row = (r & 3) + 8 * (r >> 2) + 4 * (lane >> 5);
        nxcv[r] = nx2[rbase + row];
    }

    float acc[16];
    #pragma unroll
    for (int r = 0; r < 16; ++r) acc[r] = 0.0f;

    __syncthreads();              // BsA ready (the one exposed stage wait)

    STAGE8(1, BsB);               // hidden under COMPUTE8(0)
    COMPUTE8(0, BsA);
    __syncthreads();              // drains phase-1 loads (covered)

    STAGE8(2, BsA);               // hidden under COMPUTE8(1)
    COMPUTE8(1, BsB);
    __syncthreads();              // drains phase-2 loads (covered)

    STAGE8(3, BsB);               // hidden under COMPUTE8(2)
    COMPUTE8(2, BsA);
    __syncthreads();              // drains phase-3 loads (covered)

    COMPUTE8(3, BsB);

    #undef STAGE8
    #undef COMPUTE8

    // Sum over the 32 train cols held across lanes of the same half.
    #pragma unroll
    for (int r = 0; r < 16; ++r) {
        float v = acc[r];
        v += __shfl_xor(v, 1);  v += __shfl_xor(v, 2);  v += __shfl_xor(v, 4);
        v += __shfl_xor(v, 8);  v += __shfl_xor(v, 16);
        if ((lane & 31) == 0) {
            int row = (r & 3) + 8 * (r >> 2) + 4 * (lane >> 5);
            atomicAdd(&out[rbase + row], v);
        }
    }
}

// ---------------- fallback (round-1 kernel, known-good) ----------------
#define TCHUNK 512
#define NCHUNK (NTRAIN / TCHUNK)
__global__ __launch_bounds__(256, 4) void krr_main(
    const float* __restrict__ test_X, const float* __restrict__ train_X,
    const float* __restrict__ alphas, const float* __restrict__ lengthscale,
    float* __restrict__ out)
{
    __shared__ float nt_lds[TCHUNK];
    __shared__ float al_lds[TCHUNK];
    const int tid = threadIdx.x;
    const int i   = blockIdx.x * 256 + tid;
    const int j0  = blockIdx.y * TCHUNK;
    const float ls   = lengthscale[0];
    const float inv2 = 1.0f / (ls * ls);
    for (int jj = tid; jj < TCHUNK; jj += 256) {
        const float4* tr = reinterpret_cast<const float4*>(train_X + (size_t)(j0 + jj) * DIM);
        float s = 0.f;
        #pragma unroll
        for (int k = 0; k < DIM / 4; ++k) {
            float4 t = tr[k];
            s += t.x * t.x + t.y * t.y + t.z * t.z + t.w * t.w;
        }
        nt_lds[jj] = s * inv2;
        al_lds[jj] = alphas[j0 + jj];
    }
    __syncthreads();
    float xr[DIM]; float nxv = 0.f;
    {
        const float4* xp = reinterpret_cast<const float4*>(test_X + (size_t)i * DIM);
        #pragma unroll
        for (int k = 0; k < DIM / 4; ++k) {
            float4 v = xp[k];
            xr[4*k+0] = v.x; xr[4*k+1] = v.y; xr[4*k+2] = v.z; xr[4*k+3] = v.w;
            nxv += v.x*v.x + v.y*v.y + v.z*v.z + v.w*v.w;
        }
        nxv *= inv2;
        #pragma unroll
        for (int k = 0; k < DIM; ++k) xr[k] *= inv2;
    }
    float acc = 0.f;
    for (int jj = 0; jj < TCHUNK; ++jj) {
        const float* trow = train_X + (size_t)(j0 + jj) * DIM;
        float d0 = 0.f, d1 = 0.f, d2 = 0.f, d3 = 0.f;
        #pragma unroll
        for (int k4 = 0; k4 < DIM / 4; ++k4) {
            float4 t = reinterpret_cast<const float4*>(trow)[k4];
            d0 = fmaf(xr[4*k4+0], t.x, d0);
            d1 = fmaf(xr[4*k4+1], t.y, d1);
            d2 = fmaf(xr[4*k4+2], t.z, d2);
            d3 = fmaf(xr[4*k4+3], t.w, d3);
        }
        float dot = (d0 + d1) + (d2 + d3);
        float sq  = nxv + nt_lds[jj] - 2.0f * dot;
        sq = fmaxf(sq, 0.0f);
        acc = fmaf(__expf(-0.5f * sq), al_lds[jj], acc);
    }
    atomicAdd(&out[i], acc);
}

extern "C" void kernel_launch(void* const* d_in, const int* in_sizes, int n_in,
                              void* d_out, int out_size, void* d_ws, size_t ws_size,
                              hipStream_t stream) {
    const float* test_X      = (const float*)d_in[0];
    const float* train_X     = (const float*)d_in[1];
    const float* alphas      = (const float*)d_in[2];
    const float* lengthscale = (const float*)d_in[3];
    float* out = (float*)d_out;

    const size_t need = (size_t)(NTEST + NTRAIN) * DIM * sizeof(_Float16)
                      + (NTEST + NTRAIN) * sizeof(float);
    if (ws_size >= need) {
        _Float16* A_hi = (_Float16*)d_ws;
        _Float16* B_hi = A_hi + (size_t)NTEST * DIM;
        float*    nx2  = (float*)(B_hi + (size_t)NTRAIN * DIM);
        float*    wtp  = nx2 + NTEST;

        // prep also zeroes `out` (memset launch folded in).
        krr_prep<<<(NTEST + NTRAIN) / 4, 256, 0, stream>>>(
            test_X, train_X, alphas, lengthscale, A_hi, B_hi, nx2, wtp, out);

        dim3 grid(NTEST / 256, NCOLSPLIT);
        krr_mfma<<<grid, 64 * WPB, 0, stream>>>(A_hi, B_hi, nx2, wtp,
                                                lengthscale, out);
    } else {
        hipMemsetAsync(out, 0, NTEST * sizeof(float), stream);
        dim3 grid(NTEST / 256, NCHUNK);
        krr_main<<<grid, 256, 0, stream>>>(test_X, train_X, alphas, lengthscale, out);
    }
}

// Round 24
// 37.299 us; speedup vs baseline: 1.2075x; 1.0343x over previous
//
#include <hip/hip_runtime.h>

#define NTEST  16384
#define NTRAIN 8192
#define DIM    64
#define NCOLSPLIT 16
#define WPB    8                            // waves per block (512 threads)

typedef _Float16 f16x8  __attribute__((ext_vector_type(8)));
typedef float    f32x16 __attribute__((ext_vector_type(16)));

#define LOG2E 1.4426950408889634f

// Direct global->LDS DMA: no staging VGPRs, linear wave-contiguous LDS writes.
#define GLOAD_LDS16(gsrc, ldst)                                                     \
    __builtin_amdgcn_global_load_lds(                                               \
        (const __attribute__((address_space(1))) unsigned int*)(gsrc),              \
        (__attribute__((address_space(3))) unsigned int*)(ldst), 16, 0, 0)

// Rows [0,NTEST) = test_X -> A_hi = f16(x * s1) (PRE-SCALED by inv2*log2e so
// the MFMA emits the exp argument's dot term directly) + nx2 = cn*nx
// (+ zeroes out[row]). Rows [NTEST,..) = train_X -> B_hi = f16(x) UNSCALED
// in TILE-MAJOR layout + wt = alpha * exp2(cn*nt).
// Tile-major: for train row r, dim k:
//   flat = (r>>5)*2048 + (k>>4)*512 + (((k>>3)&1)*32 + (r&31))*8 + (k&7)
__global__ __launch_bounds__(256) void krr_prep(
    const float* __restrict__ test_X, const float* __restrict__ train_X,
    const float* __restrict__ alphas, const float* __restrict__ lengthscale,
    _Float16* __restrict__ A_hi, _Float16* __restrict__ B_hi,
    float* __restrict__ nx2, float* __restrict__ wt, float* __restrict__ out)
{
    int gwave = (blockIdx.x * 256 + threadIdx.x) >> 6;
    int lane  = threadIdx.x & 63;           // = dim index k
    bool is_test = gwave < NTEST;
    int row = is_test ? gwave : gwave - NTEST;
    const float* src = is_test ? test_X : train_X;

    float ls   = lengthscale[0];
    float inv2 = 1.0f / (ls * ls);
    float s1   = inv2 * LOG2E;               // dot coefficient (log2 domain)
    float cn   = -0.5f * inv2 * LOG2E;       // norm coefficient (log2 domain)

    float x = src[(size_t)row * DIM + lane];

    if (is_test) {
        A_hi[(size_t)row * DIM + lane] = (_Float16)(x * s1);  // pre-scaled
    } else {
        _Float16 h = (_Float16)x;                             // unscaled
        int t  = row >> 5, lr = row & 31;
        int kk = lane >> 4, hi = (lane >> 3) & 1, e = lane & 7;
        size_t dst = (size_t)t * 2048 + (size_t)kk * 512 + (size_t)(hi * 32 + lr) * 8 + e;
        B_hi[dst] = h;
    }

    float s = x * x;
    s += __shfl_xor(s, 1);  s += __shfl_xor(s, 2);  s += __shfl_xor(s, 4);
    s += __shfl_xor(s, 8);  s += __shfl_xor(s, 16); s += __shfl_xor(s, 32);
    if (lane == 0) {
        if (is_test) { nx2[row] = s * cn; out[row] = 0.0f; }
        else         wt[row]  = alphas[row] * __builtin_amdgcn_exp2f(cn * s);
    }
}

// RESIDENCY EXPERIMENT (the one untried direction): r21/r22 showed waves/SIMD
// 4->2 cost +38%; this round pushes 4->6. Double-buffer shrunk to 4-TILE
// units (16+16+2 = 34KB LDS -> LDS allows 4 WG/CU); VGPR capped at 85 via
// __launch_bounds__(512,6) -> 3 WG x 8 waves = 24 waves/CU = 6/SIMD.
// Compute body drops the pair-ILP (single-tile seeded chain; at 6 waves/SIMD
// TLP replaces intra-wave ILP) to fit the cap: ah16+nxcv16+acc16+bh16+C16
// +addr ~ 82-88. GO/NO-GO on FETCH: if the cap spills, r19/r23 is the
// declared plateau. 4 phases x 4 tiles; stage-issue precedes compute so each
// barrier's vmcnt-drain is covered. Accumulation order per element unchanged
// -> absmax must stay 1.455192e-11.
// K*alpha = exp2(C[r]) * wt[col], C = cn*nx + s1*dot via seeded chain.
__global__ __launch_bounds__(512, 6) void krr_mfma(
    const _Float16* __restrict__ A_hi, const _Float16* __restrict__ B_hi,
    const float* __restrict__ nx2, const float* __restrict__ wt,
    const float* __restrict__ lengthscale, float* __restrict__ out)
{
    alignas(16) __shared__ _Float16 BsA[4 * 2048];  // 16 KB (even phases)
    alignas(16) __shared__ _Float16 BsB[4 * 2048];  // 16 KB (odd phases)
    __shared__ float wts[512];                      // 2 KB

    const int tid   = threadIdx.x;
    const int lane  = tid & 63;
    const int wave  = tid >> 6;
    const int rbase = blockIdx.x * 256 + wave * 32;
    const int cb    = blockIdx.y;                   // col-split index

    // Stage unit u (4 tiles = 16KB): wave w covers 2KB via 2 x 1KB DMA.
    #define STAGE4(u, buf)                                                      \
        {                                                                       \
            const _Float16* g = B_hi + ((size_t)cb * 16 + (u) * 4) * 2048       \
                              + (size_t)wave * 1024 + (size_t)lane * 8;         \
            _Float16* l = (buf) + (size_t)wave * 1024;                          \
            GLOAD_LDS16(g,       l);                                            \
            GLOAD_LDS16(g + 512, l + 512);                                      \
        }

    // Compute 4 tiles of phase p, one seeded chain at a time ('unroll 1' —
    // live-range barrier, spill discipline).
    #define COMPUTE4(p, buf)                                                    \
        {                                                                       \
            _Pragma("unroll 1")                                                 \
            for (int lt = 0; lt < 4; ++lt) {                                    \
                const _Float16* pt = (buf) + (size_t)lt * 2048 + (size_t)lane * 8; \
                f16x8 bh[4];                                                    \
                _Pragma("unroll")                                               \
                for (int kk = 0; kk < 4; ++kk)                                  \
                    bh[kk] = *reinterpret_cast<const f16x8*>(pt + kk * 512);    \
                f32x16 C = __builtin_amdgcn_mfma_f32_32x32x16_f16(ah[0], bh[0], nxcv, 0, 0, 0); \
                _Pragma("unroll")                                               \
                for (int kk = 1; kk < 4; ++kk)                                  \
                    C = __builtin_amdgcn_mfma_f32_32x32x16_f16(ah[kk], bh[kk], C, 0, 0, 0); \
                const float w = wts[((p) * 4 + lt) * 32 + (lane & 31)];         \
                _Pragma("unroll")                                               \
                for (int r = 0; r < 16; ++r)                                    \
                    acc[r] = fmaf(__builtin_amdgcn_exp2f(C[r]), w, acc[r]);     \
            }                                                                   \
        }

    // Issue phase-0 stage + weights immediately (512 threads, 512 wts).
    STAGE4(0, BsA);
    wts[tid] = wt[cb * 512 + tid];

    const int arow = rbase + (lane & 31);
    const int koff = (lane >> 5) * 8;        // canonical k-map, same for A and B

    // A fragments (pre-scaled by s1), loop-invariant: 4 x 16B = 16 VGPRs
    f16x8 ah[4];
    #pragma unroll
    for (int kk = 0; kk < 4; ++kk)
        ah[kk] = *reinterpret_cast<const f16x8*>(A_hi + (size_t)arow * DIM + kk * 16 + koff);

    // C-seed: cn*nx for the 16 C/D rows this lane holds.
    f32x16 nxcv;
    #pragma unroll
    for (int r = 0; r < 16; ++r) {
        int row = (r & 3) + 8 * (r >> 2) + 4 * (lane >> 5);
        nxcv[r] = nx2[rbase + row];
    }

    float acc[16];
    #pragma unroll
    for (int r = 0; r < 16; ++r) acc[r] = 0.0f;

    __syncthreads();              // BsA ready (the one exposed stage wait)

    STAGE4(1, BsB);               // hidden under COMPUTE4(0)
    COMPUTE4(0, BsA);
    __syncthreads();              // drains phase-1 loads (covered)

    STAGE4(2, BsA);               // hidden under COMPUTE4(1)
    COMPUTE4(1, BsB);
    __syncthreads();              // drains phase-2 loads (covered)

    STAGE4(3, BsB);               // hidden under COMPUTE4(2)
    COMPUTE4(2, BsA);
    __syncthreads();              // drains phase-3 loads (covered)

    COMPUTE4(3, BsB);

    #undef STAGE4
    #undef COMPUTE4

    // Sum over the 32 train cols held across lanes of the same half.
    #pragma unroll
    for (int r = 0; r < 16; ++r) {
        float v = acc[r];
        v += __shfl_xor(v, 1);  v += __shfl_xor(v, 2);  v += __shfl_xor(v, 4);
        v += __shfl_xor(v, 8);  v += __shfl_xor(v, 16);
        if ((lane & 31) == 0) {
            int row = (r & 3) + 8 * (r >> 2) + 4 * (lane >> 5);
            atomicAdd(&out[rbase + row], v);
        }
    }
}

// ---------------- fallback (round-1 kernel, known-good) ----------------
#define TCHUNK 512
#define NCHUNK (NTRAIN / TCHUNK)
__global__ __launch_bounds__(256, 4) void krr_main(
    const float* __restrict__ test_X, const float* __restrict__ train_X,
    const float* __restrict__ alphas, const float* __restrict__ lengthscale,
    float* __restrict__ out)
{
    __shared__ float nt_lds[TCHUNK];
    __shared__ float al_lds[TCHUNK];
    const int tid = threadIdx.x;
    const int i   = blockIdx.x * 256 + tid;
    const int j0  = blockIdx.y * TCHUNK;
    const float ls   = lengthscale[0];
    const float inv2 = 1.0f / (ls * ls);
    for (int jj = tid; jj < TCHUNK; jj += 256) {
        const float4* tr = reinterpret_cast<const float4*>(train_X + (size_t)(j0 + jj) * DIM);
        float s = 0.f;
        #pragma unroll
        for (int k = 0; k < DIM / 4; ++k) {
            float4 t = tr[k];
            s += t.x * t.x + t.y * t.y + t.z * t.z + t.w * t.w;
        }
        nt_lds[jj] = s * inv2;
        al_lds[jj] = alphas[j0 + jj];
    }
    __syncthreads();
    float xr[DIM]; float nxv = 0.f;
    {
        const float4* xp = reinterpret_cast<const float4*>(test_X + (size_t)i * DIM);
        #pragma unroll
        for (int k = 0; k < DIM / 4; ++k) {
            float4 v = xp[k];
            xr[4*k+0] = v.x; xr[4*k+1] = v.y; xr[4*k+2] = v.z; xr[4*k+3] = v.w;
            nxv += v.x*v.x + v.y*v.y + v.z*v.z + v.w*v.w;
        }
        nxv *= inv2;
        #pragma unroll
        for (int k = 0; k < DIM; ++k) xr[k] *= inv2;
    }
    float acc = 0.f;
    for (int jj = 0; jj < TCHUNK; ++jj) {
        const float* trow = train_X + (size_t)(j0 + jj) * DIM;
        float d0 = 0.f, d1 = 0.f, d2 = 0.f, d3 = 0.f;
        #pragma unroll
        for (int k4 = 0; k4 < DIM / 4; ++k4) {
            float4 t = reinterpret_cast<const float4*>(trow)[k4];
            d0 = fmaf(xr[4*k4+0], t.x, d0);
            d1 = fmaf(xr[4*k4+1], t.y, d1);
            d2 = fmaf(xr[4*k4+2], t.z, d2);
            d3 = fmaf(xr[4*k4+3], t.w, d3);
        }
        float dot = (d0 + d1) + (d2 + d3);
        float sq  = nxv + nt_lds[jj] - 2.0f * dot;
        sq = fmaxf(sq, 0.0f);
        acc = fmaf(__expf(-0.5f * sq), al_lds[jj], acc);
    }
    atomicAdd(&out[i], acc);
}

extern "C" void kernel_launch(void* const* d_in, const int* in_sizes, int n_in,
                              void* d_out, int out_size, void* d_ws, size_t ws_size,
                              hipStream_t stream) {
    const float* test_X      = (const float*)d_in[0];
    const float* train_X     = (const float*)d_in[1];
    const float* alphas      = (const float*)d_in[2];
    const float* lengthscale = (const float*)d_in[3];
    float* out = (float*)d_out;

    const size_t need = (size_t)(NTEST + NTRAIN) * DIM * sizeof(_Float16)
                      + (NTEST + NTRAIN) * sizeof(float);
    if (ws_size >= need) {
        _Float16* A_hi = (_Float16*)d_ws;
        _Float16* B_hi = A_hi + (size_t)NTEST * DIM;
        float*    nx2  = (float*)(B_hi + (size_t)NTRAIN * DIM);
        float*    wtp  = nx2 + NTEST;

        // prep also zeroes `out` (memset launch folded in).
        krr_prep<<<(NTEST + NTRAIN) / 4, 256, 0, stream>>>(
            test_X, train_X, alphas, lengthscale, A_hi, B_hi, nx2, wtp, out);

        dim3 grid(NTEST / 256, NCOLSPLIT);
        krr_mfma<<<grid, 64 * WPB, 0, stream>>>(A_hi, B_hi, nx2, wtp,
                                                lengthscale, out);
    } else {
        hipMemsetAsync(out, 0, NTEST * sizeof(float), stream);
        dim3 grid(NTEST / 256, NCHUNK);
        krr_main<<<grid, 256, 0, stream>>>(test_X, train_X, alphas, lengthscale, out);
    }
}